// Round 1
// baseline (269340.625 us; speedup 1.0000x reference)
//
#include <hip/hip_runtime.h>
#include <math.h>

#define TT 512
#define BB 64
#define HH 1024
#define KK 2048          // IN + H
#define NWGL 128         // WGs per layer
#define ROWS 8           // H rows per WG
#define RING_D 8         // h0 ring depth
#define BH (BB*HH)       // 65536 floats per timestep

// LDS layout (floats):
//   Wl    [ROWS][KK]        = 16384   (64 KB, resident weights)
//   buf   [4 waves][64][65] = 16640   (stride-65 transpose staging, conflict-free)
//   parts [4][64][ROWS]     = 2048    (cross-wave partial sums)
#define LDS_FLOATS (16384 + 16640 + 2048)

__device__ __forceinline__ void spin_ge(int* p, int target) {
    int it = 0;
    while (__hip_atomic_load(p, __ATOMIC_ACQUIRE, __HIP_MEMORY_SCOPE_AGENT) < target) {
        __builtin_amdgcn_s_sleep(2);
        if (++it > (1 << 21)) return;  // failsafe: fail loud (absmax), never hang
    }
}

// Stage one 1024-wide half of the input (this wave's 256-k quarter, 4 chunks of 64)
// into LDS transposed [k][b], then accumulate 8 rows.
__device__ __forceinline__ void stage_and_accum(
    const float* __restrict__ src,   // [BB][1024], row-major
    const float* __restrict__ Wl,    // LDS [ROWS][KK]
    float* __restrict__ bufW,        // this wave's [64][65] region
    int kq,                          // wave quarter offset: 256*wave
    int wof,                         // W k-offset for this half: 0 or 1024
    int lane,
    float acc[ROWS])
{
    const int bsub = lane >> 4;          // 0..3
    const int kk4  = (lane & 15) * 4;    // 0..60
    #pragma unroll
    for (int c = 0; c < 4; ++c) {
        const int k0 = kq + c * 64;
        // stage 64b x 64k, transposed to [k][b] stride 65 (2-way bank alias = free)
        #pragma unroll
        for (int i = 0; i < 16; ++i) {
            const int b = i * 4 + bsub;
            const float4 v = *(const float4*)(src + b * 1024 + k0 + kk4);
            bufW[(kk4 + 0) * 65 + b] = v.x;
            bufW[(kk4 + 1) * 65 + b] = v.y;
            bufW[(kk4 + 2) * 65 + b] = v.z;
            bufW[(kk4 + 3) * 65 + b] = v.w;
        }
        // Per-wave LDS ops are processed in order: no barrier needed (per-wave buffer).
        const float* bk = bufW + lane;
        #pragma unroll
        for (int kk = 0; kk < 64; kk += 4) {
            const float i0 = bk[(kk + 0) * 65];
            const float i1 = bk[(kk + 1) * 65];
            const float i2 = bk[(kk + 2) * 65];
            const float i3 = bk[(kk + 3) * 65];
            #pragma unroll
            for (int r = 0; r < ROWS; ++r) {
                const float4 w = *(const float4*)(Wl + r * KK + wof + k0 + kk);
                acc[r] += w.x * i0 + w.y * i1 + w.z * i2 + w.w * i3;
            }
        }
    }
}

extern "C" __global__ void rnn_init(int* __restrict__ c) {
    const int i = blockIdx.x * blockDim.x + threadIdx.x;
    if (i < 1024) c[i] = 0;
}

extern "C" __global__ void __launch_bounds__(256, 1)
rnn_persist(const float* __restrict__ x,      // [T][B][IN]
            const float* __restrict__ h0init, // [2][B][H]
            const float* __restrict__ Wih0, const float* __restrict__ bih0,
            const float* __restrict__ Whh0, const float* __restrict__ bhh0,
            const float* __restrict__ Wih1, const float* __restrict__ bih1,
            const float* __restrict__ Whh1, const float* __restrict__ bhh1,
            float* __restrict__ out,          // [T][B][H] then [2][B][H]
            int* __restrict__ c0, int* __restrict__ c1,
            float* __restrict__ ring)         // [RING_D][B][H]
{
    extern __shared__ float lds[];
    float* Wl    = lds;                      // 16384 floats
    float* buf   = lds + ROWS * KK;          // 4*64*65
    float* parts = buf + 4 * 64 * 65;        // 4*64*8

    const int wg   = blockIdx.x;
    const bool isL1 = (wg >= NWGL);
    const int g    = isL1 ? wg - NWGL : wg;
    const int rbase = g * ROWS;
    const int tid  = threadIdx.x;
    const int wv   = tid >> 6;
    const int lane = tid & 63;
    const int kq   = wv * 256;
    float* bufW = buf + wv * (64 * 65);

    // Load this WG's weight rows into LDS once (resident for all 512 steps).
    const float* Wa = isL1 ? Wih1 : Wih0;    // k-half 0 (input half)
    const float* Wb = isL1 ? Whh1 : Whh0;    // k-half 1 (recurrent half)
    for (int idx = tid; idx < ROWS * 256; idx += 256) {
        const int r  = idx >> 8;
        const int k4 = (idx & 255) * 4;
        *(float4*)(Wl + r * KK + k4)        = *(const float4*)(Wa + (size_t)(rbase + r) * HH + k4);
        *(float4*)(Wl + r * KK + 1024 + k4) = *(const float4*)(Wb + (size_t)(rbase + r) * HH + k4);
    }
    const int er = tid & 7;  // output row (same for tid and tid+256)
    const float bsum = isL1 ? (bih1[rbase + er] + bhh1[rbase + er])
                            : (bih0[rbase + er] + bhh0[rbase + er]);
    __syncthreads();

    for (int t = 0; t < TT; ++t) {
        float acc[ROWS];
        #pragma unroll
        for (int r = 0; r < ROWS; ++r) acc[r] = 0.f;

        if (!isL1) {
            // Phase A: x[t] half — no dependency, hides the wait below.
            stage_and_accum(x + (size_t)t * BH, Wl, bufW, kq, 0, lane, acc);
            if (tid == 0) {
                if (t >= 1)      spin_ge(c0 + (t - 1), NWGL);      // h0[t-1] ready
                if (t >= RING_D) spin_ge(c1 + (t - RING_D), NWGL); // ring slot reusable
            }
            __syncthreads();
            // Phase B: h0[t-1] half (recurrent, W_hh0 => wof 1024)
            const float* hp = (t == 0) ? h0init
                                       : ring + (size_t)((t - 1) % RING_D) * BH;
            stage_and_accum(hp, Wl, bufW, kq, 1024, lane, acc);
        } else {
            if (tid == 0 && t >= 1) spin_ge(c1 + (t - 1), NWGL);   // h1[t-1] ready
            __syncthreads();
            // Phase A: h1[t-1] half (recurrent, W_hh1 => wof 1024)
            const float* hp = (t == 0) ? (h0init + BH)
                                       : (out + (size_t)(t - 1) * BH);
            stage_and_accum(hp, Wl, bufW, kq, 1024, lane, acc);
            if (tid == 0) spin_ge(c0 + t, NWGL);                   // h0[t] ready
            __syncthreads();
            // Phase B: h0[t] half (input half, W_ih1 => wof 0)
            stage_and_accum(ring + (size_t)(t % RING_D) * BH, Wl, bufW, kq, 0, lane, acc);
        }

        // Cross-wave reduction: partials [w][b][r]
        float* pw = parts + (size_t)(wv * 64 + lane) * ROWS;
        *(float4*)(pw + 0) = make_float4(acc[0], acc[1], acc[2], acc[3]);
        *(float4*)(pw + 4) = make_float4(acc[4], acc[5], acc[6], acc[7]);
        __syncthreads();

        for (int o = tid; o < 512; o += 256) {
            const int b = o >> 3;
            const int r = o & 7;
            const float s = parts[o] + parts[o + 512] + parts[o + 1024] + parts[o + 1536] + bsum;
            const float hv = tanhf(s);
            const int col = rbase + r;
            if (!isL1) {
                ring[(size_t)(t % RING_D) * BH + b * HH + col] = hv;
                if (t == TT - 1) out[(size_t)TT * BH + b * HH + col] = hv;          // h0_n
            } else {
                out[(size_t)t * BH + b * HH + col] = hv;                            // outputs
                if (t == TT - 1) out[(size_t)TT * BH + BH + b * HH + col] = hv;     // h1_n
            }
        }
        __syncthreads();  // drains all stores (vmcnt 0) before publish
        if (tid == 0) {
            __hip_atomic_fetch_add(isL1 ? (c1 + t) : (c0 + t), 1,
                                   __ATOMIC_RELEASE, __HIP_MEMORY_SCOPE_AGENT);
        }
    }
}

extern "C" void kernel_launch(void* const* d_in, const int* in_sizes, int n_in,
                              void* d_out, int out_size, void* d_ws, size_t ws_size,
                              hipStream_t stream) {
    const float* x    = (const float*)d_in[0];
    const float* h0i  = (const float*)d_in[1];
    const float* Wih0 = (const float*)d_in[2];
    const float* bih0 = (const float*)d_in[3];
    const float* Whh0 = (const float*)d_in[4];
    const float* bhh0 = (const float*)d_in[5];
    const float* Wih1 = (const float*)d_in[6];
    const float* bih1 = (const float*)d_in[7];
    const float* Whh1 = (const float*)d_in[8];
    const float* bhh1 = (const float*)d_in[9];
    float* out = (float*)d_out;

    int*   c0   = (int*)d_ws;             // [512]
    int*   c1   = c0 + 512;               // [512]
    float* ring = (float*)((char*)d_ws + 8192);  // [RING_D][B][H]

    (void)hipFuncSetAttribute((const void*)rnn_persist,
                              hipFuncAttributeMaxDynamicSharedMemorySize,
                              LDS_FLOATS * 4);

    rnn_init<<<4, 256, 0, stream>>>(c0);
    rnn_persist<<<256, 256, LDS_FLOATS * 4, stream>>>(
        x, h0i, Wih0, bih0, Whh0, bhh0, Wih1, bih1, Whh1, bhh1,
        out, c0, c1, ring);
}

// Round 2
// 241745.239 us; speedup vs baseline: 1.1142x; 1.1142x over previous
//
#include <hip/hip_runtime.h>
#include <math.h>

#define TT 512
#define BB 64
#define HH 1024
#define KK 2048          // IN + H
#define NWGL 128         // WGs per layer
#define ROWS 8           // H rows per WG
#define RING_D 8         // h0 ring depth
#define BH (BB*HH)       // 65536 floats per timestep

// LDS layout (floats):
//   Wl    [ROWS][KK]        = 16384   (64 KB, resident weights)
//   buf   [4 waves][64][65] = 16640   (stride-65 transpose staging, conflict-free)
//   parts [4][64][ROWS]     = 2048    (cross-wave partial sums)
#define LDS_FLOATS (16384 + 16640 + 2048)

// RELAXED probe: plain coherent load of the counter line only — NO cache-wide
// invalidate per probe (the R1 ACQUIRE probe emitted buffer_inv every ~50ns,
// thrashing the XCD L2 -> 470GB TCC traffic). One __threadfence() after the
// spin does the acquire-side invalidate exactly once per wait-point.
__device__ __forceinline__ void spin_ge(int* p, int target) {
    int it = 0;
    while (__hip_atomic_load(p, __ATOMIC_RELAXED, __HIP_MEMORY_SCOPE_AGENT) < target) {
        __builtin_amdgcn_s_sleep(4);
        if (++it > (1 << 21)) return;  // failsafe: fail loud (absmax), never hang
    }
}

// Stage one 1024-wide half of the input (this wave's 256-k quarter, 4 chunks of 64)
// into LDS transposed [k][b], then accumulate 8 rows.
__device__ __forceinline__ void stage_and_accum(
    const float* __restrict__ src,   // [BB][1024], row-major
    const float* __restrict__ Wl,    // LDS [ROWS][KK]
    float* __restrict__ bufW,        // this wave's [64][65] region
    int kq,                          // wave quarter offset: 256*wave
    int wof,                         // W k-offset for this half: 0 or 1024
    int lane,
    float acc[ROWS])
{
    const int bsub = lane >> 4;          // 0..3
    const int kk4  = (lane & 15) * 4;    // 0..60
    #pragma unroll
    for (int c = 0; c < 4; ++c) {
        const int k0 = kq + c * 64;
        // stage 64b x 64k, transposed to [k][b] stride 65 (2-way bank alias = free)
        #pragma unroll
        for (int i = 0; i < 16; ++i) {
            const int b = i * 4 + bsub;
            const float4 v = *(const float4*)(src + b * 1024 + k0 + kk4);
            bufW[(kk4 + 0) * 65 + b] = v.x;
            bufW[(kk4 + 1) * 65 + b] = v.y;
            bufW[(kk4 + 2) * 65 + b] = v.z;
            bufW[(kk4 + 3) * 65 + b] = v.w;
        }
        // Per-wave LDS ops are processed in order: no barrier needed (per-wave buffer).
        const float* bk = bufW + lane;
        #pragma unroll
        for (int kk = 0; kk < 64; kk += 4) {
            const float i0 = bk[(kk + 0) * 65];
            const float i1 = bk[(kk + 1) * 65];
            const float i2 = bk[(kk + 2) * 65];
            const float i3 = bk[(kk + 3) * 65];
            #pragma unroll
            for (int r = 0; r < ROWS; ++r) {
                const float4 w = *(const float4*)(Wl + r * KK + wof + k0 + kk);
                acc[r] += w.x * i0 + w.y * i1 + w.z * i2 + w.w * i3;
            }
        }
    }
}

extern "C" __global__ void rnn_init(int* __restrict__ c) {
    const int i = blockIdx.x * blockDim.x + threadIdx.x;
    if (i < 1024) c[i] = 0;
}

extern "C" __global__ void __launch_bounds__(256, 1)
rnn_persist(const float* __restrict__ x,      // [T][B][IN]
            const float* __restrict__ h0init, // [2][B][H]
            const float* __restrict__ Wih0, const float* __restrict__ bih0,
            const float* __restrict__ Whh0, const float* __restrict__ bhh0,
            const float* __restrict__ Wih1, const float* __restrict__ bih1,
            const float* __restrict__ Whh1, const float* __restrict__ bhh1,
            float* __restrict__ out,          // [T][B][H] then [2][B][H]
            int* __restrict__ c0, int* __restrict__ c1,
            float* __restrict__ ring)         // [RING_D][B][H]
{
    extern __shared__ float lds[];
    float* Wl    = lds;                      // 16384 floats
    float* buf   = lds + ROWS * KK;          // 4*64*65
    float* parts = buf + 4 * 64 * 65;        // 4*64*8

    const int wg   = blockIdx.x;
    const bool isL1 = (wg >= NWGL);
    const int g    = isL1 ? wg - NWGL : wg;
    const int rbase = g * ROWS;
    const int tid  = threadIdx.x;
    const int wv   = tid >> 6;
    const int lane = tid & 63;
    const int kq   = wv * 256;
    float* bufW = buf + wv * (64 * 65);

    // Load this WG's weight rows into LDS once (resident for all 512 steps).
    const float* Wa = isL1 ? Wih1 : Wih0;    // k-half 0 (input half)
    const float* Wb = isL1 ? Whh1 : Whh0;    // k-half 1 (recurrent half)
    for (int idx = tid; idx < ROWS * 256; idx += 256) {
        const int r  = idx >> 8;
        const int k4 = (idx & 255) * 4;
        *(float4*)(Wl + r * KK + k4)        = *(const float4*)(Wa + (size_t)(rbase + r) * HH + k4);
        *(float4*)(Wl + r * KK + 1024 + k4) = *(const float4*)(Wb + (size_t)(rbase + r) * HH + k4);
    }
    const int er = tid & 7;  // output row (same for tid and tid+256)
    const float bsum = isL1 ? (bih1[rbase + er] + bhh1[rbase + er])
                            : (bih0[rbase + er] + bhh0[rbase + er]);
    __syncthreads();

    for (int t = 0; t < TT; ++t) {
        float acc[ROWS];
        #pragma unroll
        for (int r = 0; r < ROWS; ++r) acc[r] = 0.f;

        if (!isL1) {
            // Phase A: x[t] half — no dependency, hides the wait below.
            stage_and_accum(x + (size_t)t * BH, Wl, bufW, kq, 0, lane, acc);
            if (tid == 0) {
                if (t >= 1)      spin_ge(c0 + (t - 1), NWGL);      // h0[t-1] ready
                if (t >= RING_D) spin_ge(c1 + (t - RING_D), NWGL); // ring slot reusable
                if (t >= 1) __threadfence();   // single acquire inv per step
            }
            __syncthreads();
            // Phase B: h0[t-1] half (recurrent, W_hh0 => wof 1024)
            const float* hp = (t == 0) ? h0init
                                       : ring + (size_t)((t - 1) % RING_D) * BH;
            stage_and_accum(hp, Wl, bufW, kq, 1024, lane, acc);
        } else {
            if (tid == 0 && t >= 1) {
                spin_ge(c1 + (t - 1), NWGL);   // h1[t-1] ready
                __threadfence();
            }
            __syncthreads();
            // Phase A: h1[t-1] half (recurrent, W_hh1 => wof 1024)
            const float* hp = (t == 0) ? (h0init + BH)
                                       : (out + (size_t)(t - 1) * BH);
            stage_and_accum(hp, Wl, bufW, kq, 1024, lane, acc);
            if (tid == 0) {
                spin_ge(c0 + t, NWGL);         // h0[t] ready
                __threadfence();
            }
            __syncthreads();
            // Phase B: h0[t] half (input half, W_ih1 => wof 0)
            stage_and_accum(ring + (size_t)(t % RING_D) * BH, Wl, bufW, kq, 0, lane, acc);
        }

        // Cross-wave reduction: partials [w][b][r]
        float* pw = parts + (size_t)(wv * 64 + lane) * ROWS;
        *(float4*)(pw + 0) = make_float4(acc[0], acc[1], acc[2], acc[3]);
        *(float4*)(pw + 4) = make_float4(acc[4], acc[5], acc[6], acc[7]);
        __syncthreads();

        for (int o = tid; o < 512; o += 256) {
            const int b = o >> 3;
            const int r = o & 7;
            const float s = parts[o] + parts[o + 512] + parts[o + 1024] + parts[o + 1536] + bsum;
            const float hv = tanhf(s);
            const int col = rbase + r;
            if (!isL1) {
                ring[(size_t)(t % RING_D) * BH + b * HH + col] = hv;
                if (t == TT - 1) out[(size_t)TT * BH + b * HH + col] = hv;          // h0_n
            } else {
                out[(size_t)t * BH + b * HH + col] = hv;                            // outputs
                if (t == TT - 1) out[(size_t)TT * BH + BH + b * HH + col] = hv;     // h1_n
            }
        }
        __syncthreads();  // drains all WG stores to L2 before publish
        if (tid == 0) {
            __threadfence();  // release: write dirty L2 back to coherence point
            __hip_atomic_fetch_add(isL1 ? (c1 + t) : (c0 + t), 1,
                                   __ATOMIC_RELAXED, __HIP_MEMORY_SCOPE_AGENT);
        }
    }
}

extern "C" void kernel_launch(void* const* d_in, const int* in_sizes, int n_in,
                              void* d_out, int out_size, void* d_ws, size_t ws_size,
                              hipStream_t stream) {
    const float* x    = (const float*)d_in[0];
    const float* h0i  = (const float*)d_in[1];
    const float* Wih0 = (const float*)d_in[2];
    const float* bih0 = (const float*)d_in[3];
    const float* Whh0 = (const float*)d_in[4];
    const float* bhh0 = (const float*)d_in[5];
    const float* Wih1 = (const float*)d_in[6];
    const float* bih1 = (const float*)d_in[7];
    const float* Whh1 = (const float*)d_in[8];
    const float* bhh1 = (const float*)d_in[9];
    float* out = (float*)d_out;

    int*   c0   = (int*)d_ws;             // [512]
    int*   c1   = c0 + 512;               // [512]
    float* ring = (float*)((char*)d_ws + 8192);  // [RING_D][B][H]

    (void)hipFuncSetAttribute((const void*)rnn_persist,
                              hipFuncAttributeMaxDynamicSharedMemorySize,
                              LDS_FLOATS * 4);

    rnn_init<<<4, 256, 0, stream>>>(c0);
    rnn_persist<<<256, 256, LDS_FLOATS * 4, stream>>>(
        x, h0i, Wih0, bih0, Whh0, bhh0, Wih1, bih1, Whh1, bhh1,
        out, c0, c1, ring);
}